// Round 1
// baseline (126.935 us; speedup 1.0000x reference)
//
#include <hip/hip_runtime.h>
#include <hip/hip_bf16.h>
#include <stdint.h>

typedef __attribute__((ext_vector_type(8))) short bf8_t;   // 8 bf16 in 4 VGPRs
typedef __attribute__((ext_vector_type(4))) short s4_t;
typedef __attribute__((ext_vector_type(4))) float f4_t;
typedef unsigned short u16;

#define GLOAD16(g, l) __builtin_amdgcn_global_load_lds(                                  \
    (const __attribute__((address_space(1))) void*)(g),                                  \
    (__attribute__((address_space(3))) void*)(l), 16, 0, 0)

__device__ __forceinline__ u16 f2bf(float f) {
    union { float f; unsigned u; } c; c.f = f;
    unsigned u = c.u;
    return (u16)((u + 0x7fffu + ((u >> 16) & 1u)) >> 16);   // RNE, inputs finite
}

// ---------------- weights -> bf16 ----------------
__global__ void prep_kernel(const float* __restrict__ wq, const float* __restrict__ wk,
                            const float* __restrict__ wv, const float* __restrict__ wp,
                            const float* __restrict__ bq, const float* __restrict__ bk,
                            const float* __restrict__ bv,
                            u16* __restrict__ wcat, u16* __restrict__ wpb,
                            float* __restrict__ biasc) {
    int idx = blockIdx.x * 256 + threadIdx.x;
    if (idx < 196608) {                 // wcat [768][256]
        int o = idx >> 8, c = idx & 255;
        float v = (o < 256) ? wq[o * 256 + c]
                : (o < 512) ? wk[(o - 256) * 256 + c]
                            : wv[(o - 512) * 256 + c];
        wcat[idx] = f2bf(v);
    } else if (idx < 262144) {          // wp [256][256]
        wpb[idx - 196608] = f2bf(wp[idx - 196608]);
    } else if (idx < 262912) {          // bias concat [768]
        int i = idx - 262144;
        biasc[i] = (i < 256) ? bq[i] : (i < 512) ? bk[i - 256] : bv[i - 512];
    }
}

// ---------------- LayerNorm over C, write hn [B*N][C] bf16 ----------------
__global__ __launch_bounds__(64) void ln_kernel(const float* __restrict__ x,
                                                const float* __restrict__ lw,
                                                const float* __restrict__ lb,
                                                u16* __restrict__ hn) {
    int tok = blockIdx.x * 64 + threadIdx.x;          // 0..16383
    int b = tok >> 10, n = tok & 1023;
    const float* xb = x + (size_t)b * 262144 + n;     // x[b][c][n], stride 1024
    float s = 0.f, s2 = 0.f;
    #pragma unroll 8
    for (int c = 0; c < 256; c++) { float v = xb[(size_t)c * 1024]; s += v; s2 += v * v; }
    float mean = s * 0.00390625f;
    float var  = s2 * 0.00390625f - mean * mean;      // biased var
    float rstd = rsqrtf(var + 1e-6f);
    u16* hr = hn + (size_t)tok * 256;
    for (int c0 = 0; c0 < 256; c0 += 8) {
        bf8_t pk;
        #pragma unroll
        for (int j = 0; j < 8; j++) {
            float v = xb[(size_t)(c0 + j) * 1024];
            float y = (v - mean) * rstd * lw[c0 + j] + lb[c0 + j];
            pk[j] = (short)f2bf(y);
        }
        *(bf8_t*)&hr[c0] = pk;                        // 16B contiguous store
    }
}

// ---------------- generic B^T bf16 GEMM, 128x128 tile, m97 structure ----------------
// C[m][n] = sum_k A[m][k]*B[n][k]; EPI: 0=QKV(+bias,bf16) 1=S(*scale,f32) 2=O(bf16) 3=PROJ(+bias+resid,f32)
template <int EPI>
__global__ __launch_bounds__(256, 2) void gemm_bt(
    const u16* __restrict__ A, const u16* __restrict__ B, void* __restrict__ Cp,
    int lda, int ldb, int ldc, int nk,
    long sA, long sB, long sC,
    const float* __restrict__ aux1, const float* __restrict__ aux2) {
    __shared__ u16 lsA[128 * 32];
    __shared__ u16 lsB[128 * 32];
    const int tid = threadIdx.x;
    const int z = blockIdx.z;
    const int m0 = blockIdx.x * 128, n0 = blockIdx.y * 128;
    const int lane = tid & 63;
    const int w = tid >> 6, wm = w >> 1, wn = w & 1;    // 2x2 waves, 64x64 each
    const int lm = lane & 15, lg = lane >> 4;
    const int sr = tid >> 2, sc = (tid & 3) * 8;        // staging row/chunk

    const u16* ga = A + (size_t)z * sA + (size_t)(m0 + sr) * lda + sc;
    const u16* gb = B + (size_t)z * sB + (size_t)(n0 + sr) * ldb + sc;
    u16* la  = &lsA[sr * 32 + sc];                      // linear: byte off = tid*16
    u16* lb2 = &lsB[sr * 32 + sc];

    f4_t acc[4][4];
    #pragma unroll
    for (int i = 0; i < 4; i++)
        #pragma unroll
        for (int j = 0; j < 4; j++) acc[i][j] = (f4_t)0.0f;

    for (int kt = 0; kt < nk; ++kt) {
        GLOAD16(ga, la);
        GLOAD16(ga + (size_t)64 * lda, la + 64 * 32);
        GLOAD16(gb, lb2);
        GLOAD16(gb + (size_t)64 * ldb, lb2 + 64 * 32);
        ga += 32; gb += 32;
        __syncthreads();                                // drains vmcnt before use
        bf8_t af[4], bfv[4];
        #pragma unroll
        for (int i = 0; i < 4; i++)
            af[i] = *(const bf8_t*)&lsA[(wm * 64 + i * 16 + lm) * 32 + lg * 8];
        #pragma unroll
        for (int i = 0; i < 4; i++)
            bfv[i] = *(const bf8_t*)&lsB[(wn * 64 + i * 16 + lm) * 32 + lg * 8];
        #pragma unroll
        for (int i = 0; i < 4; i++)
            #pragma unroll
            for (int j = 0; j < 4; j++)
                acc[i][j] = __builtin_amdgcn_mfma_f32_16x16x32_bf16(af[i], bfv[j], acc[i][j], 0, 0, 0);
        __syncthreads();                                // before next-tile overwrite
    }

    const int rb = m0 + wm * 64 + lg * 4;
    const int cb = n0 + wn * 64 + lm;
    #pragma unroll
    for (int i = 0; i < 4; i++)
        #pragma unroll
        for (int j = 0; j < 4; j++)
            #pragma unroll
            for (int r = 0; r < 4; r++) {
                int row = rb + i * 16 + r;
                int col = cb + j * 16;
                float v = acc[i][j][r];
                if (EPI == 0) {
                    ((u16*)Cp)[(size_t)row * ldc + col] = f2bf(v + aux1[col]);
                } else if (EPI == 1) {
                    ((float*)Cp)[(size_t)z * sC + (size_t)row * ldc + col] = v * 0.0625f;
                } else if (EPI == 2) {
                    ((u16*)Cp)[(size_t)z * sC + (size_t)row * ldc + col] = f2bf(v);
                } else {
                    size_t idx = (size_t)z * sC + (size_t)row * ldc + col;
                    ((float*)Cp)[idx] = v + aux1[row] + aux2[idx];
                }
            }
}

// ---------------- V transpose: qkv[tok][512+c] -> vt[b][c][n] ----------------
__global__ __launch_bounds__(256) void transpose_v(const u16* __restrict__ qkv,
                                                   u16* __restrict__ vt) {
    int n0 = blockIdx.x * 32, c0 = blockIdx.y * 32, b = blockIdx.z;
    __shared__ u16 tile[32][33];
    int t = threadIdx.x;
    int r = t >> 3, q = t & 7;
    const u16* src = qkv + (size_t)(b * 1024 + n0 + r) * 768 + 512 + c0 + q * 4;
    s4_t v = *(const s4_t*)src;
    #pragma unroll
    for (int j = 0; j < 4; j++) tile[r][q * 4 + j] = (u16)v[j];
    __syncthreads();
    u16* dst = vt + (size_t)b * 262144 + (size_t)(c0 + r) * 1024 + n0 + q * 4;
    s4_t o;
    #pragma unroll
    for (int j = 0; j < 4; j++) o[j] = (short)tile[q * 4 + j][r];
    *(s4_t*)dst = o;
}

// ---------------- row softmax: S fp32 [16384][1024] -> P bf16 ----------------
__global__ __launch_bounds__(256) void softmax_kernel(const float* __restrict__ S,
                                                      u16* __restrict__ P) {
    int row = blockIdx.x;
    int t = threadIdx.x, w = t >> 6, lane = t & 63;
    const float4* Sr = (const float4*)(S + (size_t)row * 1024);
    float4 v = Sr[t];
    float m = fmaxf(fmaxf(v.x, v.y), fmaxf(v.z, v.w));
    #pragma unroll
    for (int o = 32; o; o >>= 1) m = fmaxf(m, __shfl_xor(m, o));
    __shared__ float redm[4], reds[4];
    if (lane == 0) redm[w] = m;
    __syncthreads();
    m = fmaxf(fmaxf(redm[0], redm[1]), fmaxf(redm[2], redm[3]));
    float4 e;
    e.x = __expf(v.x - m); e.y = __expf(v.y - m);
    e.z = __expf(v.z - m); e.w = __expf(v.w - m);
    float s = e.x + e.y + e.z + e.w;
    #pragma unroll
    for (int o = 32; o; o >>= 1) s += __shfl_xor(s, o);
    if (lane == 0) reds[w] = s;
    __syncthreads();
    s = reds[0] + reds[1] + reds[2] + reds[3];
    float inv = 1.0f / s;
    s4_t pk;
    pk[0] = (short)f2bf(e.x * inv); pk[1] = (short)f2bf(e.y * inv);
    pk[2] = (short)f2bf(e.z * inv); pk[3] = (short)f2bf(e.w * inv);
    *(s4_t*)&P[(size_t)row * 1024 + t * 4] = pk;
}

extern "C" void kernel_launch(void* const* d_in, const int* in_sizes, int n_in,
                              void* d_out, int out_size, void* d_ws, size_t ws_size,
                              hipStream_t stream) {
    (void)in_sizes; (void)n_in; (void)out_size; (void)ws_size;
    const float* x   = (const float*)d_in[0];
    const float* lnw = (const float*)d_in[1];
    const float* lnb = (const float*)d_in[2];
    const float* wq  = (const float*)d_in[3];
    const float* bq  = (const float*)d_in[4];
    const float* wk  = (const float*)d_in[5];
    const float* bk  = (const float*)d_in[6];
    const float* wv  = (const float*)d_in[7];
    const float* bv  = (const float*)d_in[8];
    const float* wp  = (const float*)d_in[9];
    const float* bp  = (const float*)d_in[10];
    float* out = (float*)d_out;

    char* ws = (char*)d_ws;                 // ~152 MB total
    u16*   wcat  = (u16*)(ws);              // 768*256 bf16
    u16*   wpb   = (u16*)(ws + 0x60000);    // 256*256 bf16
    float* biasc = (float*)(ws + 0x80000);  // 768 f32
    u16*   hn    = (u16*)(ws + 0x90000);    // 16384*256 bf16   (8MB)
    u16*   qkv   = (u16*)(ws + 0x890000);   // 16384*768 bf16   (24MB)
    u16*   vt    = (u16*)(ws + 0x2090000);  // 16*256*1024 bf16 (8MB)
    float* S     = (float*)(ws + 0x2890000);// 16*1024*1024 f32 (64MB)
    u16*   P     = (u16*)(ws + 0x6890000);  // 16*1024*1024 bf16(32MB)
    u16*   O     = (u16*)(ws + 0x8890000);  // 16384*256 bf16   (8MB)

    prep_kernel<<<1028, 256, 0, stream>>>(wq, wk, wv, wp, bq, bk, bv, wcat, wpb, biasc);
    ln_kernel<<<256, 64, 0, stream>>>(x, lnw, lnb, hn);
    // QKV: [16384,768] = hn[16384,256] x wcat[768,256]^T  (+bias, bf16)
    gemm_bt<0><<<dim3(128, 6, 1), 256, 0, stream>>>(hn, wcat, qkv, 256, 256, 768, 8,
                                                    0, 0, 0, biasc, nullptr);
    transpose_v<<<dim3(32, 8, 16), 256, 0, stream>>>(qkv, vt);
    // S[b] = Q[b] x K[b]^T * 1/16  (f32)
    gemm_bt<1><<<dim3(8, 8, 16), 256, 0, stream>>>(qkv, qkv + 256, S, 768, 768, 1024, 8,
                                                   786432, 786432, 1048576, nullptr, nullptr);
    softmax_kernel<<<16384, 256, 0, stream>>>(S, P);
    // O[b] = P[b] x V[b]  (B-op = vt rows=channels, K=tokens)
    gemm_bt<2><<<dim3(8, 2, 16), 256, 0, stream>>>(P, vt, O, 1024, 1024, 256, 32,
                                                   1048576, 262144, 262144, nullptr, nullptr);
    // out[b] = wp x O[b]^T + bp + x  (f32)
    gemm_bt<3><<<dim3(2, 8, 16), 256, 0, stream>>>(wpb, O, out, 256, 256, 1024, 8,
                                                   0, 262144, 262144, bp, x);
}

// Round 2
// 97.366 us; speedup vs baseline: 1.3037x; 1.3037x over previous
//
#include <hip/hip_runtime.h>
#include <hip/hip_bf16.h>
#include <stdint.h>

typedef __attribute__((ext_vector_type(8))) short bf8_t;   // 8 bf16 in 4 VGPRs
typedef __attribute__((ext_vector_type(4))) short s4_t;
typedef __attribute__((ext_vector_type(4))) float f4_t;
typedef unsigned short u16;

#define GLOAD16(g, l) __builtin_amdgcn_global_load_lds(                                  \
    (const __attribute__((address_space(1))) void*)(g),                                  \
    (__attribute__((address_space(3))) void*)(l), 16, 0, 0)

__device__ __forceinline__ u16 f2bf(float f) {
    union { float f; unsigned u; } c; c.f = f;
    unsigned u = c.u;
    return (u16)((u + 0x7fffu + ((u >> 16) & 1u)) >> 16);   // RNE, inputs finite
}

// ---------------- weights -> bf16 ----------------
__global__ void prep_kernel(const float* __restrict__ wq, const float* __restrict__ wk,
                            const float* __restrict__ wv, const float* __restrict__ wp,
                            const float* __restrict__ bq, const float* __restrict__ bk,
                            const float* __restrict__ bv,
                            u16* __restrict__ wcat, u16* __restrict__ wpb,
                            float* __restrict__ biasc) {
    int idx = blockIdx.x * 256 + threadIdx.x;
    if (idx < 196608) {                 // wcat [768][256]
        int o = idx >> 8, c = idx & 255;
        float v = (o < 256) ? wq[o * 256 + c]
                : (o < 512) ? wk[(o - 256) * 256 + c]
                            : wv[(o - 512) * 256 + c];
        wcat[idx] = f2bf(v);
    } else if (idx < 262144) {          // wp [256][256]
        wpb[idx - 196608] = f2bf(wp[idx - 196608]);
    } else if (idx < 262912) {          // bias concat [768]
        int i = idx - 262144;
        biasc[i] = (i < 256) ? bq[i] : (i < 512) ? bk[i - 256] : bv[i - 512];
    }
}

// ---------------- LayerNorm over C, single-pass, 8 waves/CU ----------------
// block = 512 threads: tok_local = tid&63, cgroup = tid>>6 (8 groups x 32 ch)
__global__ __launch_bounds__(512) void ln_kernel(const float* __restrict__ x,
                                                 const float* __restrict__ lw,
                                                 const float* __restrict__ lb,
                                                 u16* __restrict__ hn) {
    int tid = threadIdx.x;
    int tl = tid & 63, cg = tid >> 6;
    int tok = blockIdx.x * 64 + tl;
    int b = tok >> 10, n = tok & 1023;
    const float* xb = x + (size_t)b * 262144 + n;     // stride 1024 over c
    int ch0 = cg * 32;
    float v[32];
    float s = 0.f, s2 = 0.f;
    #pragma unroll
    for (int j = 0; j < 32; j++) {
        v[j] = xb[(size_t)(ch0 + j) * 1024];
        s += v[j]; s2 += v[j] * v[j];
    }
    __shared__ float2 red[8][64];
    red[cg][tl] = make_float2(s, s2);
    __syncthreads();
    s = 0.f; s2 = 0.f;
    #pragma unroll
    for (int g = 0; g < 8; g++) { float2 p = red[g][tl]; s += p.x; s2 += p.y; }
    float mean = s * 0.00390625f;
    float var  = s2 * 0.00390625f - mean * mean;
    float rstd = rsqrtf(var + 1e-6f);
    u16* hr = hn + (size_t)tok * 256 + ch0;
    #pragma unroll
    for (int j8 = 0; j8 < 4; j8++) {
        bf8_t pk;
        #pragma unroll
        for (int j = 0; j < 8; j++) {
            int c = j8 * 8 + j;
            float y = (v[c] - mean) * rstd * lw[ch0 + c] + lb[ch0 + c];
            pk[j] = (short)f2bf(y);
        }
        *(bf8_t*)&hr[j8 * 8] = pk;
    }
}

// ---------------- generic B^T bf16 GEMM, 128x128 tile, m97 structure ----------------
// EPI: 0 = QKV (+bias, bf16 out)   3 = PROJ (+bias + residual, f32 out)
template <int EPI>
__global__ __launch_bounds__(256, 2) void gemm_bt(
    const u16* __restrict__ A, const u16* __restrict__ B, void* __restrict__ Cp,
    int lda, int ldb, int ldc, int nk,
    long sA, long sB, long sC,
    const float* __restrict__ aux1, const float* __restrict__ aux2) {
    __shared__ u16 lsA[128 * 32];
    __shared__ u16 lsB[128 * 32];
    const int tid = threadIdx.x;
    const int z = blockIdx.z;
    const int m0 = blockIdx.x * 128, n0 = blockIdx.y * 128;
    const int lane = tid & 63;
    const int w = tid >> 6, wm = w >> 1, wn = w & 1;
    const int lm = lane & 15, lg = lane >> 4;
    const int sr = tid >> 2, sc = (tid & 3) * 8;

    const u16* ga = A + (size_t)z * sA + (size_t)(m0 + sr) * lda + sc;
    const u16* gb = B + (size_t)z * sB + (size_t)(n0 + sr) * ldb + sc;
    u16* la  = &lsA[sr * 32 + sc];
    u16* lb2 = &lsB[sr * 32 + sc];

    f4_t acc[4][4];
    #pragma unroll
    for (int i = 0; i < 4; i++)
        #pragma unroll
        for (int j = 0; j < 4; j++) acc[i][j] = (f4_t)0.0f;

    for (int kt = 0; kt < nk; ++kt) {
        GLOAD16(ga, la);
        GLOAD16(ga + (size_t)64 * lda, la + 64 * 32);
        GLOAD16(gb, lb2);
        GLOAD16(gb + (size_t)64 * ldb, lb2 + 64 * 32);
        ga += 32; gb += 32;
        __syncthreads();
        bf8_t af[4], bfv[4];
        #pragma unroll
        for (int i = 0; i < 4; i++)
            af[i] = *(const bf8_t*)&lsA[(wm * 64 + i * 16 + lm) * 32 + lg * 8];
        #pragma unroll
        for (int i = 0; i < 4; i++)
            bfv[i] = *(const bf8_t*)&lsB[(wn * 64 + i * 16 + lm) * 32 + lg * 8];
        #pragma unroll
        for (int i = 0; i < 4; i++)
            #pragma unroll
            for (int j = 0; j < 4; j++)
                acc[i][j] = __builtin_amdgcn_mfma_f32_16x16x32_bf16(af[i], bfv[j], acc[i][j], 0, 0, 0);
        __syncthreads();
    }

    const int rb = m0 + wm * 64 + lg * 4;
    const int cb = n0 + wn * 64 + lm;
    #pragma unroll
    for (int i = 0; i < 4; i++)
        #pragma unroll
        for (int j = 0; j < 4; j++)
            #pragma unroll
            for (int r = 0; r < 4; r++) {
                int row = rb + i * 16 + r;
                int col = cb + j * 16;
                float v = acc[i][j][r];
                if (EPI == 0) {
                    ((u16*)Cp)[(size_t)row * ldc + col] = f2bf(v + aux1[col]);
                } else {
                    size_t idx = (size_t)z * sC + (size_t)row * ldc + col;
                    ((float*)Cp)[idx] = v + aux1[row] + aux2[idx];
                }
            }
}

// ---------------- V transpose: qkv[tok][512+c] -> vt[b][c][n] ----------------
__global__ __launch_bounds__(256) void transpose_v(const u16* __restrict__ qkv,
                                                   u16* __restrict__ vt) {
    int n0 = blockIdx.x * 32, c0 = blockIdx.y * 32, b = blockIdx.z;
    __shared__ u16 tile[32][33];
    int t = threadIdx.x;
    int r = t >> 3, q = t & 7;
    const u16* src = qkv + (size_t)(b * 1024 + n0 + r) * 768 + 512 + c0 + q * 4;
    s4_t v = *(const s4_t*)src;
    #pragma unroll
    for (int j = 0; j < 4; j++) tile[r][q * 4 + j] = (u16)v[j];
    __syncthreads();
    u16* dst = vt + (size_t)b * 262144 + (size_t)(c0 + r) * 1024 + n0 + q * 4;
    s4_t o;
    #pragma unroll
    for (int j = 0; j < 4; j++) o[j] = (short)tile[q * 4 + j][r];
    *(s4_t*)dst = o;
}

// ---------------- flash attention: O = softmax(Q K^T / 16) V ----------------
// grid = 256 blocks (XCD-swizzled -> (b, qb)), 256 threads = 4 waves.
// Wave w owns q rows qb*64 + w*16 .. +15. KV tiles of 64, double-buffered LDS.
__global__ __launch_bounds__(256, 1) void flash_kernel(const u16* __restrict__ qkv,
                                                       const u16* __restrict__ vt,
                                                       u16* __restrict__ O) {
    __shared__ u16 K_lds[2][64 * 256];   // [kv][c], XOR-swizzled rows (32 chunks)
    __shared__ u16 V_lds[2][256 * 64];   // [d][kv], XOR-swizzled rows (8 chunks)
    __shared__ u16 P_lds[4][16 * 72];    // per-wave P tile, padded stride 72

    const int flat = blockIdx.x;
    const int xcd = flat & 7, idx = flat >> 3;
    const int b = (xcd << 1) | (idx & 1);     // 2 batches per XCD -> KV fits L2
    const int qb = idx >> 1;
    const int tid = threadIdx.x;
    const int w = tid >> 6, lane = tid & 63, lm = lane & 15, lg = lane >> 4;

    // Q fragments in registers: A[row=lm][k=lg*8..] per k-chunk
    const int qrow = qb * 64 + w * 16 + lm;
    const u16* qptr = qkv + (size_t)(b * 1024 + qrow) * 768 + lg * 8;
    bf8_t qf[8];
    #pragma unroll
    for (int kc = 0; kc < 8; kc++) qf[kc] = *(const bf8_t*)(qptr + kc * 32);

    float m_r[4], l_r[4];
    f4_t o_acc[16];
    #pragma unroll
    for (int r = 0; r < 4; r++) { m_r[r] = -1e30f; l_r[r] = 0.f; }
    #pragma unroll
    for (int j = 0; j < 16; j++) o_acc[j] = (f4_t)0.0f;

    const size_t kvbase = (size_t)b * 1024 * 768 + 256;   // K block in qkv
    const size_t vbase  = (size_t)b * 262144;             // vt batch

#define STAGE(T, BUF)                                                               \
    {                                                                               \
        int kvb = (T) * 64;                                                         \
        _Pragma("unroll")                                                           \
        for (int it = 0; it < 8; ++it) {                                            \
            int cid = it * 256 + tid;                                               \
            int row = cid >> 5, cc = cid & 31;                                      \
            const u16* g = qkv + kvbase + (size_t)(kvb + row) * 768                 \
                               + (size_t)((cc ^ (row & 7)) * 8);                    \
            GLOAD16(g, &K_lds[BUF][cid * 8]);                                       \
        }                                                                           \
        _Pragma("unroll")                                                           \
        for (int it = 0; it < 8; ++it) {                                            \
            int cid = it * 256 + tid;                                               \
            int row = cid >> 3, cc = cid & 7;                                       \
            const u16* g = vt + vbase + (size_t)row * 1024 + kvb                    \
                              + (size_t)((cc ^ (row & 7)) * 8);                     \
            GLOAD16(g, &V_lds[BUF][cid * 8]);                                       \
        }                                                                           \
    }

    STAGE(0, 0);
    __syncthreads();

    for (int t = 0; t < 16; ++t) {
        const int buf = t & 1;
        if (t < 15) STAGE(t + 1, buf ^ 1);

        // ---- QK^T: S[q16][kv64] per wave ----
        f4_t s_acc[4];
        #pragma unroll
        for (int i = 0; i < 4; i++) s_acc[i] = (f4_t)0.0f;
        #pragma unroll
        for (int kc = 0; kc < 8; kc++)
            #pragma unroll
            for (int i = 0; i < 4; i++) {
                int row = i * 16 + lm;
                int boff = row * 512 + ((kc * 64 + lg * 16) ^ ((row & 7) << 4));
                bf8_t kf = *(const bf8_t*)((const char*)&K_lds[buf][0] + boff);
                s_acc[i] = __builtin_amdgcn_mfma_f32_16x16x32_bf16(qf[kc], kf, s_acc[i], 0, 0, 0);
            }

        // ---- online softmax (rows lg*4+r, cols i*16+lm) ----
        #pragma unroll
        for (int i = 0; i < 4; i++)
            #pragma unroll
            for (int r = 0; r < 4; r++) s_acc[i][r] *= 0.0625f;

        float corr[4];
        #pragma unroll
        for (int r = 0; r < 4; r++) {
            float tm = fmaxf(fmaxf(s_acc[0][r], s_acc[1][r]), fmaxf(s_acc[2][r], s_acc[3][r]));
            #pragma unroll
            for (int o = 1; o < 16; o <<= 1) tm = fmaxf(tm, __shfl_xor(tm, o));
            float mn = fmaxf(m_r[r], tm);
            corr[r] = __expf(m_r[r] - mn);
            m_r[r] = mn;
        }
        float ts[4] = {0.f, 0.f, 0.f, 0.f};
        #pragma unroll
        for (int i = 0; i < 4; i++)
            #pragma unroll
            for (int r = 0; r < 4; r++) {
                float p = __expf(s_acc[i][r] - m_r[r]);
                s_acc[i][r] = p;
                ts[r] += p;
            }
        #pragma unroll
        for (int r = 0; r < 4; r++) {
            float t2 = ts[r];
            #pragma unroll
            for (int o = 1; o < 16; o <<= 1) t2 += __shfl_xor(t2, o);
            l_r[r] = l_r[r] * corr[r] + t2;
        }
        #pragma unroll
        for (int j = 0; j < 16; j++)
            #pragma unroll
            for (int r = 0; r < 4; r++) o_acc[j][r] *= corr[r];

        // P -> LDS (per-wave, padded) to re-enter MFMA A-layout
        #pragma unroll
        for (int i = 0; i < 4; i++)
            #pragma unroll
            for (int r = 0; r < 4; r++)
                P_lds[w][(lg * 4 + r) * 72 + i * 16 + lm] = f2bf(s_acc[i][r]);

        // ---- PV: O += P[q16][kv64] x V^T ----
        #pragma unroll
        for (int kc2 = 0; kc2 < 2; kc2++) {
            bf8_t pa = *(const bf8_t*)&P_lds[w][lm * 72 + kc2 * 32 + lg * 8];
            #pragma unroll
            for (int j = 0; j < 16; j++) {
                int row = j * 16 + lm;
                int boff = row * 128 + ((kc2 * 64 + lg * 16) ^ ((row & 7) << 4));
                bf8_t vf = *(const bf8_t*)((const char*)&V_lds[buf][0] + boff);
                o_acc[j] = __builtin_amdgcn_mfma_f32_16x16x32_bf16(pa, vf, o_acc[j], 0, 0, 0);
            }
        }
        __syncthreads();   // prefetch landed + all waves done with buf
    }

    // ---- epilogue: O /= l, write bf16 ----
    float inv[4];
    #pragma unroll
    for (int r = 0; r < 4; r++) inv[r] = 1.0f / l_r[r];
    const int orow = qb * 64 + w * 16 + lg * 4;
    #pragma unroll
    for (int j = 0; j < 16; j++)
        #pragma unroll
        for (int r = 0; r < 4; r++)
            O[(size_t)(b * 1024 + orow + r) * 256 + j * 16 + lm] = f2bf(o_acc[j][r] * inv[r]);
#undef STAGE
}

extern "C" void kernel_launch(void* const* d_in, const int* in_sizes, int n_in,
                              void* d_out, int out_size, void* d_ws, size_t ws_size,
                              hipStream_t stream) {
    (void)in_sizes; (void)n_in; (void)out_size; (void)ws_size;
    const float* x   = (const float*)d_in[0];
    const float* lnw = (const float*)d_in[1];
    const float* lnb = (const float*)d_in[2];
    const float* wq  = (const float*)d_in[3];
    const float* bq  = (const float*)d_in[4];
    const float* wk  = (const float*)d_in[5];
    const float* bk  = (const float*)d_in[6];
    const float* wv  = (const float*)d_in[7];
    const float* bv  = (const float*)d_in[8];
    const float* wp  = (const float*)d_in[9];
    const float* bp  = (const float*)d_in[10];
    float* out = (float*)d_out;

    char* ws = (char*)d_ws;
    u16*   wcat  = (u16*)(ws);              // 768*256 bf16
    u16*   wpb   = (u16*)(ws + 0x60000);    // 256*256 bf16
    float* biasc = (float*)(ws + 0x80000);  // 768 f32
    u16*   hn    = (u16*)(ws + 0x90000);    // 16384*256 bf16   (8MB)
    u16*   qkv   = (u16*)(ws + 0x890000);   // 16384*768 bf16   (24MB)
    u16*   vt    = (u16*)(ws + 0x2090000);  // 16*256*1024 bf16 (8MB)
    u16*   O     = (u16*)(ws + 0x2890000);  // 16384*256 bf16   (8MB)

    prep_kernel<<<1028, 256, 0, stream>>>(wq, wk, wv, wp, bq, bk, bv, wcat, wpb, biasc);
    ln_kernel<<<256, 512, 0, stream>>>(x, lnw, lnb, hn);
    // QKV: [16384,768] = hn[16384,256] x wcat[768,256]^T  (+bias, bf16)
    gemm_bt<0><<<dim3(128, 6, 1), 256, 0, stream>>>(hn, wcat, qkv, 256, 256, 768, 8,
                                                    0, 0, 0, biasc, nullptr);
    transpose_v<<<dim3(32, 8, 16), 256, 0, stream>>>(qkv, vt);
    // fused attention
    flash_kernel<<<256, 256, 0, stream>>>(qkv, vt, O);
    // out[b] = wp x O[b]^T + bp + x  (f32)
    gemm_bt<3><<<dim3(2, 8, 16), 256, 0, stream>>>(wpb, O, out, 256, 256, 1024, 8,
                                                   0, 262144, 262144, bp, x);
}